// Round 4
// baseline (256.782 us; speedup 1.0000x reference)
//
#include <hip/hip_runtime.h>
#include <hip/hip_bf16.h>
#include <stdint.h>

#define Hdim 512
#define KC   32768

typedef __hip_bfloat16 bf16;
typedef __attribute__((ext_vector_type(8))) short short8;
typedef __attribute__((ext_vector_type(4))) float float4v;

// pack two fp32 -> two bf16 (truncation) in one v_perm_b32; low16 = trunc(e0)
__device__ __forceinline__ unsigned int pack_bf16_trunc(float e0, float e1) {
  union { float f; unsigned int u; } a, b;
  a.f = e0; b.f = e1;
  return __builtin_amdgcn_perm(b.u, a.u, 0x07060302u);
}

// ---------------- launch 1: prep (blocks 0..7) + WT transpose (blocks 8..71) ----
// 1024 threads/block.
__global__ __launch_bounds__(1024) void prep_wt_kernel(
    const float* __restrict__ input_, const float* __restrict__ h_0,
    const float* __restrict__ w_ih, const float* __restrict__ w_hh,
    const float* __restrict__ a_w_ih, const float* __restrict__ a_w_hh,
    float* __restrict__ gates, float* __restrict__ awi, bf16* __restrict__ wt) {
  const int t = threadIdx.x;
  if (blockIdx.x < 8) {
    // prep: thread (js, ds) accumulates output j over d-range ds*128..+128; no atomics
    __shared__ float h0s[Hdim], ins[Hdim];
    __shared__ float red[4][256];
    const int js = t & 255, ds = t >> 8;
    for (int i = t; i < Hdim; i += 1024) { h0s[i] = h_0[i]; ins[i] = input_[i]; }
    __syncthreads();
    const int j = blockIdx.x * 256 + js;   // 0..2047 (uniform branch per block)
    float acc = 0.f;
    if (j < 1536) {
#pragma unroll 8
      for (int d = ds * 128; d < ds * 128 + 128; ++d)
        acc += h0s[d] * w_hh[(size_t)d * 1536 + j] + ins[d] * w_ih[(size_t)d * 1536 + j];
    } else {
      const int jj = j - 1536;
#pragma unroll 8
      for (int d = ds * 128; d < ds * 128 + 128; ++d)
        acc += ins[d] * a_w_ih[(size_t)d * Hdim + jj];
    }
    red[ds][js] = acc;
    __syncthreads();
    if (t < 256) {
      const int jo = blockIdx.x * 256 + t;
      float s = red[0][t] + red[1][t] + red[2][t] + red[3][t];
      if (jo < 1536) gates[jo] = s;
      else           awi[jo - 1536] = s;
    }
  } else {
    // WT[h][d] = bf16(W[d][h]), 64x64 tiles
    __shared__ float tile[64][65];
    const int b = blockIdx.x - 8;
    const int d0 = (b & 7) * 64, h0 = (b >> 3) * 64;
    const int tx = t & 63, tw = t >> 6;  // tw 0..15
#pragma unroll
    for (int r = 0; r < 4; ++r) {
      const int row = r * 16 + tw;
      tile[row][tx] = a_w_hh[(size_t)(d0 + row) * Hdim + h0 + tx];
    }
    __syncthreads();
#pragma unroll
    for (int r = 0; r < 4; ++r) {
      const int row = r * 16 + tw;
      wt[(size_t)(h0 + row) * Hdim + d0 + tx] = __float2bfloat16(tile[tx][row]);
    }
  }
}

// ---------------- launch 2: LDS-free fused GEMM + sigmoid/exp + K-partial reduce ----
// 1024 blocks, 256 threads = 4 waves. Wave: 16 m-rows x 256 n. No K-loop barriers.
__global__ __launch_bounds__(256) void gemm_reduce_kernel(
    const float* __restrict__ c_input, const bf16* __restrict__ WT,
    const float* __restrict__ awi,
    float* __restrict__ pw, float* __restrict__ pwc) {
  __shared__ float red_w[4][256];
  __shared__ float red_wc[4][256];

  const int tid  = threadIdx.x;
  const int lane = tid & 63;
  const int wv   = tid >> 6;
  const int lm   = lane & 15;
  const int lq   = lane >> 4;

  // XCD swizzle: ids id and id+8 (the two n-halves of one kk-slab) share id&7 -> same XCD
  const int id     = blockIdx.x;
  const int kk_idx = ((id >> 4) << 3) | (id & 7);   // 0..511
  const int h_idx  = (id >> 3) & 1;                 // 0..1
  const int m0 = kk_idx * 64 + wv * 16;             // wave's 16 rows
  const int n0 = h_idx * 256;

  float4v acc[16];
#pragma unroll
  for (int i = 0; i < 16; ++i) acc[i] = (float4v){0.f, 0.f, 0.f, 0.f};

  const float* arow = c_input + (size_t)(m0 + lm) * Hdim;  // lane's A row (A[m=lm][k])

#pragma unroll 2
  for (int ks = 0; ks < 16; ++ks) {
    const int kb = ks * 32 + lq * 8;
    // A fragment: 8 consecutive fp32 -> bf16 (2 dwordx4 + 4 perms)
    float4v a0 = *(const float4v*)(arow + kb);
    float4v a1 = *(const float4v*)(arow + kb + 4);
    union { unsigned int u[4]; short8 s; } af;
    af.u[0] = pack_bf16_trunc(a0[0], a0[1]);
    af.u[1] = pack_bf16_trunc(a0[2], a0[3]);
    af.u[2] = pack_bf16_trunc(a1[0], a1[1]);
    af.u[3] = pack_bf16_trunc(a1[2], a1[3]);
    // B fragments in two batches of 8 (cap live VGPRs); L1-served (waves share addrs)
    short8 bf0[8], bf1[8];
#pragma unroll
    for (int nt = 0; nt < 8; ++nt)
      bf0[nt] = *(const short8*)(WT + (size_t)(n0 + nt * 16 + lm) * Hdim + kb);
#pragma unroll
    for (int nt = 0; nt < 8; ++nt)
      acc[nt] = __builtin_amdgcn_mfma_f32_16x16x32_bf16(af.s, bf0[nt], acc[nt], 0, 0, 0);
#pragma unroll
    for (int nt = 0; nt < 8; ++nt)
      bf1[nt] = *(const short8*)(WT + (size_t)(n0 + (nt + 8) * 16 + lm) * Hdim + kb);
#pragma unroll
    for (int nt = 0; nt < 8; ++nt)
      acc[nt + 8] = __builtin_amdgcn_mfma_f32_16x16x32_bf16(af.s, bf1[nt], acc[nt + 8], 0, 0, 0);
  }

  // epilogue: alpha = sigmoid(acc + awi[n]); accumulate exp(alpha), exp(alpha)*c
  // C/D: col = lm = n, row = lq*4 + r = m
#pragma unroll
  for (int nt = 0; nt < 16; ++nt) {
    const int n = n0 + nt * 16 + lm;
    const float aw = awi[n];
    float sw = 0.f, swc = 0.f;
#pragma unroll
    for (int r = 0; r < 4; ++r) {
      float v = acc[nt][r] + aw;
      float alpha = 1.f / (1.f + __expf(-v));
      float e = __expf(alpha);
      float c = c_input[(size_t)(m0 + lq * 4 + r) * Hdim + n];  // L2-hot (same XCD)
      sw  += e;
      swc += e * c;
    }
    sw  += __shfl_xor(sw, 16, 64);
    sw  += __shfl_xor(sw, 32, 64);
    swc += __shfl_xor(swc, 16, 64);
    swc += __shfl_xor(swc, 32, 64);
    if (lq == 0) {
      red_w[wv][nt * 16 + lm]  = sw;
      red_wc[wv][nt * 16 + lm] = swc;
    }
  }
  __syncthreads();
  {
    float s  = red_w[0][tid] + red_w[1][tid] + red_w[2][tid] + red_w[3][tid];
    float sc = red_wc[0][tid] + red_wc[1][tid] + red_wc[2][tid] + red_wc[3][tid];
    pw[(size_t)kk_idx * Hdim + n0 + tid]  = s;
    pwc[(size_t)kk_idx * Hdim + n0 + tid] = sc;
  }
}

// ---------------- launch 3: final reduction + LSTM merge ----------------
// 8 blocks x 1024: block covers 64 h, 16-way split over 512 m-blocks
__global__ __launch_bounds__(1024) void finalize_kernel(
    const float* __restrict__ pw, const float* __restrict__ pwc,
    const float* __restrict__ gates, const float* __restrict__ bias,
    float* __restrict__ out) {
  __shared__ float rsw[16][64], rswc[16][64];
  const int t = threadIdx.x;
  const int hl = t & 63, q = t >> 6;   // q 0..15
  const int hh = blockIdx.x * 64 + hl;
  float sw = 0.f, swc = 0.f;
#pragma unroll 8
  for (int kb = q * 32; kb < q * 32 + 32; ++kb) {
    sw  += pw[(size_t)kb * Hdim + hh];
    swc += pwc[(size_t)kb * Hdim + hh];
  }
  rsw[q][hl] = sw; rswc[q][hl] = swc;
  __syncthreads();
  if (t < 64) {
    const int h = blockIdx.x * 64 + t;
    sw = 0.f; swc = 0.f;
#pragma unroll
    for (int qq = 0; qq < 16; ++qq) { sw += rsw[qq][t]; swc += rswc[qq][t]; }
    float ipre = gates[h] + bias[h];
    float opre = gates[Hdim + h] + bias[Hdim + h];
    float gpre = gates[2 * Hdim + h] + bias[2 * Hdim + h];
    float ei = expf(1.f / (1.f + expf(-ipre)));   // exp(sigmoid(i))
    float g  = tanhf(gpre);
    float o  = 1.f / (1.f + expf(-opre));
    float denom = ei + sw + 1e-12f;
    float c1 = (ei * g + swc) / denom;
    float h1 = o * tanhf(c1);
    out[h]        = h1;
    out[Hdim + h] = c1;
  }
}

extern "C" void kernel_launch(void* const* d_in, const int* in_sizes, int n_in,
                              void* d_out, int out_size, void* d_ws, size_t ws_size,
                              hipStream_t stream) {
  const float* input_  = (const float*)d_in[0];
  const float* c_input = (const float*)d_in[1];
  const float* h_0     = (const float*)d_in[2];
  /* d_in[3] = c_0: unused by the reference's taken branch */
  const float* w_ih    = (const float*)d_in[4];
  const float* w_hh    = (const float*)d_in[5];
  const float* bias    = (const float*)d_in[6];
  const float* a_w_ih  = (const float*)d_in[7];
  const float* a_w_hh  = (const float*)d_in[8];

  char* ws = (char*)d_ws;
  float* pw    = (float*)ws;                           // 512*512 f32 = 1 MB
  float* pwc   = (float*)(ws + 1024 * 1024);           // 1 MB
  float* gates = (float*)(ws + 2 * 1024 * 1024);       // 6 KB
  float* awi   = (float*)(ws + 2 * 1024 * 1024 + 6144);// 2 KB
  bf16*  WT    = (bf16*)(ws + 2 * 1024 * 1024 + 8192); // 512 KB

  hipLaunchKernelGGL(prep_wt_kernel, dim3(72), dim3(1024), 0, stream,
                     input_, h_0, w_ih, w_hh, a_w_ih, a_w_hh, gates, awi, WT);
  hipLaunchKernelGGL(gemm_reduce_kernel, dim3(1024), dim3(256), 0, stream,
                     c_input, WT, awi, pw, pwc);
  hipLaunchKernelGGL(finalize_kernel, dim3(8), dim3(1024), 0, stream,
                     pw, pwc, gates, bias, (float*)d_out);
}

// Round 5
// 154.051 us; speedup vs baseline: 1.6669x; 1.6669x over previous
//
#include <hip/hip_runtime.h>
#include <hip/hip_bf16.h>
#include <stdint.h>

#define Hdim 512
#define KC   32768

typedef __hip_bfloat16 bf16;
typedef __attribute__((ext_vector_type(8))) short short8;
typedef __attribute__((ext_vector_type(4))) float float4v;
typedef __attribute__((ext_vector_type(4))) unsigned int uint4v;

// pack two fp32 -> two bf16 (truncation) in one v_perm_b32; low16 = trunc(e0)
__device__ __forceinline__ unsigned int pack_bf16_trunc(float e0, float e1) {
  union { float f; unsigned int u; } a, b;
  a.f = e0; b.f = e1;
  return __builtin_amdgcn_perm(b.u, a.u, 0x07060302u);
}

// ---------------- launch 1: prep (blocks 0..7) + WT transpose (blocks 8..71) ----
__global__ __launch_bounds__(1024) void prep_wt_kernel(
    const float* __restrict__ input_, const float* __restrict__ h_0,
    const float* __restrict__ w_ih, const float* __restrict__ w_hh,
    const float* __restrict__ a_w_ih, const float* __restrict__ a_w_hh,
    float* __restrict__ gates, float* __restrict__ awi, bf16* __restrict__ wt) {
  const int t = threadIdx.x;
  if (blockIdx.x < 8) {
    __shared__ float h0s[Hdim], ins[Hdim];
    __shared__ float red[4][256];
    const int js = t & 255, ds = t >> 8;
    for (int i = t; i < Hdim; i += 1024) { h0s[i] = h_0[i]; ins[i] = input_[i]; }
    __syncthreads();
    const int j = blockIdx.x * 256 + js;
    float acc = 0.f;
    if (j < 1536) {
#pragma unroll 8
      for (int d = ds * 128; d < ds * 128 + 128; ++d)
        acc += h0s[d] * w_hh[(size_t)d * 1536 + j] + ins[d] * w_ih[(size_t)d * 1536 + j];
    } else {
      const int jj = j - 1536;
#pragma unroll 8
      for (int d = ds * 128; d < ds * 128 + 128; ++d)
        acc += ins[d] * a_w_ih[(size_t)d * Hdim + jj];
    }
    red[ds][js] = acc;
    __syncthreads();
    if (t < 256) {
      const int jo = blockIdx.x * 256 + t;
      float s = red[0][t] + red[1][t] + red[2][t] + red[3][t];
      if (jo < 1536) gates[jo] = s;
      else           awi[jo - 1536] = s;
    }
  } else {
    __shared__ float tile[64][65];
    const int b = blockIdx.x - 8;
    const int d0 = (b & 7) * 64, h0 = (b >> 3) * 64;
    const int tx = t & 63, tw = t >> 6;
#pragma unroll
    for (int r = 0; r < 4; ++r) {
      const int row = r * 16 + tw;
      tile[row][tx] = a_w_hh[(size_t)(d0 + row) * Hdim + h0 + tx];
    }
    __syncthreads();
#pragma unroll
    for (int r = 0; r < 4; ++r) {
      const int row = r * 16 + tw;
      wt[(size_t)(h0 + row) * Hdim + d0 + tx] = __float2bfloat16(tile[tx][row]);
    }
  }
}

// ---------------- launch 2: pipelined fused GEMM + sigmoid/exp + K-partial reduce ----
// 1024 blocks (XCD-swizzled), 256 threads = 4 waves (2x2). Register prefetch of
// iteration i+1's global data overlaps MFMA of iteration i (short-K stall fix).
__global__ __launch_bounds__(256) void gemm_reduce_kernel(
    const float* __restrict__ c_input, const bf16* __restrict__ WT,
    const float* __restrict__ awi,
    float* __restrict__ pw, float* __restrict__ pwc) {
  __shared__ __align__(16) bf16 As[128 * 64];   // swizzled [row][g^(row&7)]
  __shared__ __align__(16) bf16 Bs[128 * 64];   // swizzled
  __shared__ float red_w[2][128];
  __shared__ float red_wc[2][128];

  const int tid  = threadIdx.x;
  const int lane = tid & 63;
  const int wv   = tid >> 6;
  const int wm   = wv & 1;
  const int wn   = wv >> 1;
  const int lm   = lane & 15;
  const int lq   = lane >> 4;

  // XCD swizzle: 4 h-blocks of one kk-slab share id&7 -> same XCD, adjacent ids
  const int id     = blockIdx.x;
  const int kk_idx = ((id >> 5) << 3) | (id & 7);   // 0..255
  const int h_idx  = (id >> 3) & 3;                 // 0..3
  const int kk0 = kk_idx * 128;
  const int h0  = h_idx * 128;

  // staging thread mappings
  const int ar_base = tid >> 3;               // A row = j*32 + ar_base
  const int acol    = (tid & 7) * 8;          // fp32 col offset in 64-chunk
  const int aga     = tid & 7;                // A granule (pre-xor)
  const int br_base = wv * 8 + (lane >> 3);   // B row = r*32 + br_base
  const int bg      = (lane & 7) ^ (lane >> 3);
  const int bcol    = (lane & 7) * 8;         // bf16 col offset

  float4v acc[4][4];
#pragma unroll
  for (int i = 0; i < 4; ++i)
#pragma unroll
    for (int j = 0; j < 4; ++j)
      acc[i][j] = (float4v){0.f, 0.f, 0.f, 0.f};

  char* AsB = (char*)As;
  char* BsB = (char*)Bs;

  // prologue prefetch (d0 = 0)
  float4v pa0[4], pa1[4];
  short8  pb[4];
#pragma unroll
  for (int j = 0; j < 4; ++j) {
    const float* p = c_input + (size_t)(kk0 + j * 32 + ar_base) * Hdim + acol;
    pa0[j] = *(const float4v*)p;
    pa1[j] = *(const float4v*)(p + 4);
  }
#pragma unroll
  for (int r = 0; r < 4; ++r)
    pb[r] = *(const short8*)(WT + (size_t)(h0 + r * 32 + br_base) * Hdim + bcol);

#pragma unroll 1
  for (int it = 0; it < 8; ++it) {
    __syncthreads();   // previous iteration's readers done
    // regs -> LDS (A repacked to bf16, single b128 per j)
#pragma unroll
    for (int j = 0; j < 4; ++j) {
      const int row = j * 32 + ar_base;
      uint4v u;
      u[0] = pack_bf16_trunc(pa0[j][0], pa0[j][1]);
      u[1] = pack_bf16_trunc(pa0[j][2], pa0[j][3]);
      u[2] = pack_bf16_trunc(pa1[j][0], pa1[j][1]);
      u[3] = pack_bf16_trunc(pa1[j][2], pa1[j][3]);
      *(uint4v*)(AsB + row * 128 + ((aga ^ (row & 7)) * 16)) = u;
    }
#pragma unroll
    for (int r = 0; r < 4; ++r) {
      const int row = r * 32 + br_base;
      *(short8*)(BsB + row * 128 + bg * 16) = pb[r];
    }
    __syncthreads();   // writes visible
    // issue next iteration's global loads NOW -> latency hides under MFMA
    if (it < 7) {
      const int d0 = (it + 1) * 64;
#pragma unroll
      for (int j = 0; j < 4; ++j) {
        const float* p = c_input + (size_t)(kk0 + j * 32 + ar_base) * Hdim + d0 + acol;
        pa0[j] = *(const float4v*)p;
        pa1[j] = *(const float4v*)(p + 4);
      }
#pragma unroll
      for (int r = 0; r < 4; ++r)
        pb[r] = *(const short8*)(WT + (size_t)(h0 + r * 32 + br_base) * Hdim + d0 + bcol);
    }
    // MFMA block
#pragma unroll
    for (int ks = 0; ks < 2; ++ks) {
      short8 a[4], b[4];
#pragma unroll
      for (int mt = 0; mt < 4; ++mt) {
        const int row = wm * 64 + mt * 16 + lm;
        a[mt] = *(const short8*)(AsB + row * 128 + (((ks * 4 + lq) ^ (lm & 7)) * 16));
      }
#pragma unroll
      for (int nt = 0; nt < 4; ++nt) {
        const int row = wn * 64 + nt * 16 + lm;
        b[nt] = *(const short8*)(BsB + row * 128 + (((ks * 4 + lq) ^ (lm & 7)) * 16));
      }
#pragma unroll
      for (int mt = 0; mt < 4; ++mt)
#pragma unroll
        for (int nt = 0; nt < 4; ++nt)
          acc[mt][nt] = __builtin_amdgcn_mfma_f32_16x16x32_bf16(a[mt], b[nt], acc[mt][nt], 0, 0, 0);
    }
  }

  // epilogue: alpha = sigmoid(acc + awi[h]); accumulate exp(alpha), exp(alpha)*c
  float awi_l[4];
#pragma unroll
  for (int nt = 0; nt < 4; ++nt)
    awi_l[nt] = awi[h0 + wn * 64 + nt * 16 + lm];

  float sw[4] = {0.f, 0.f, 0.f, 0.f}, swc[4] = {0.f, 0.f, 0.f, 0.f};
#pragma unroll
  for (int nt = 0; nt < 4; ++nt) {
    const int h = h0 + wn * 64 + nt * 16 + lm;
#pragma unroll
    for (int mt = 0; mt < 4; ++mt) {
      const int kkb = kk0 + wm * 64 + mt * 16 + lq * 4;
#pragma unroll
      for (int r = 0; r < 4; ++r) {
        float v = acc[mt][nt][r] + awi_l[nt];
        float alpha = 1.f / (1.f + __expf(-v));
        float e = __expf(alpha);
        float c = c_input[(size_t)(kkb + r) * Hdim + h];  // L2-hot (same XCD)
        sw[nt]  += e;
        swc[nt] += e * c;
      }
    }
  }
#pragma unroll
  for (int nt = 0; nt < 4; ++nt) {
    sw[nt]  += __shfl_xor(sw[nt], 16, 64);
    sw[nt]  += __shfl_xor(sw[nt], 32, 64);
    swc[nt] += __shfl_xor(swc[nt], 16, 64);
    swc[nt] += __shfl_xor(swc[nt], 32, 64);
  }
  if (lq == 0) {
#pragma unroll
    for (int nt = 0; nt < 4; ++nt) {
      red_w[wm][wn * 64 + nt * 16 + lm]  = sw[nt];
      red_wc[wm][wn * 64 + nt * 16 + lm] = swc[nt];
    }
  }
  __syncthreads();
  if (tid < 128) {
    pw[(size_t)kk_idx * Hdim + h0 + tid]  = red_w[0][tid] + red_w[1][tid];
    pwc[(size_t)kk_idx * Hdim + h0 + tid] = red_wc[0][tid] + red_wc[1][tid];
  }
}

// ---------------- launch 3: final reduction + LSTM merge ----------------
// 8 blocks x 1024: block covers 64 h, 16-way split over 256 m-slabs
__global__ __launch_bounds__(1024) void finalize_kernel(
    const float* __restrict__ pw, const float* __restrict__ pwc,
    const float* __restrict__ gates, const float* __restrict__ bias,
    float* __restrict__ out) {
  __shared__ float rsw[16][64], rswc[16][64];
  const int t = threadIdx.x;
  const int hl = t & 63, q = t >> 6;
  const int hh = blockIdx.x * 64 + hl;
  float sw = 0.f, swc = 0.f;
#pragma unroll 8
  for (int kb = q * 16; kb < q * 16 + 16; ++kb) {
    sw  += pw[(size_t)kb * Hdim + hh];
    swc += pwc[(size_t)kb * Hdim + hh];
  }
  rsw[q][hl] = sw; rswc[q][hl] = swc;
  __syncthreads();
  if (t < 64) {
    const int h = blockIdx.x * 64 + t;
    sw = 0.f; swc = 0.f;
#pragma unroll
    for (int qq = 0; qq < 16; ++qq) { sw += rsw[qq][t]; swc += rswc[qq][t]; }
    float ipre = gates[h] + bias[h];
    float opre = gates[Hdim + h] + bias[Hdim + h];
    float gpre = gates[2 * Hdim + h] + bias[2 * Hdim + h];
    float ei = expf(1.f / (1.f + expf(-ipre)));   // exp(sigmoid(i))
    float g  = tanhf(gpre);
    float o  = 1.f / (1.f + expf(-opre));
    float denom = ei + sw + 1e-12f;
    float c1 = (ei * g + swc) / denom;
    float h1 = o * tanhf(c1);
    out[h]        = h1;
    out[Hdim + h] = c1;
  }
}

extern "C" void kernel_launch(void* const* d_in, const int* in_sizes, int n_in,
                              void* d_out, int out_size, void* d_ws, size_t ws_size,
                              hipStream_t stream) {
  const float* input_  = (const float*)d_in[0];
  const float* c_input = (const float*)d_in[1];
  const float* h_0     = (const float*)d_in[2];
  /* d_in[3] = c_0: unused by the reference's taken branch */
  const float* w_ih    = (const float*)d_in[4];
  const float* w_hh    = (const float*)d_in[5];
  const float* bias    = (const float*)d_in[6];
  const float* a_w_ih  = (const float*)d_in[7];
  const float* a_w_hh  = (const float*)d_in[8];

  char* ws = (char*)d_ws;
  float* pw    = (float*)ws;                           // 256*512 f32 = 512 KB
  float* pwc   = (float*)(ws + 512 * 1024);            // 512 KB
  float* gates = (float*)(ws + 1024 * 1024);           // 6 KB
  float* awi   = (float*)(ws + 1024 * 1024 + 6144);    // 2 KB
  bf16*  WT    = (bf16*)(ws + 1024 * 1024 + 8192);     // 512 KB

  hipLaunchKernelGGL(prep_wt_kernel, dim3(72), dim3(1024), 0, stream,
                     input_, h_0, w_ih, w_hh, a_w_ih, a_w_hh, gates, awi, WT);
  hipLaunchKernelGGL(gemm_reduce_kernel, dim3(1024), dim3(256), 0, stream,
                     c_input, WT, awi, pw, pwc);
  hipLaunchKernelGGL(finalize_kernel, dim3(8), dim3(1024), 0, stream,
                     pw, pwc, gates, bias, (float*)d_out);
}